// Round 15
// baseline (47.470 us; speedup 1.0000x reference)
//
#include <hip/hip_runtime.h>
#include <hip/hip_bf16.h>
#include <math.h>

#define NN 4096
#define CC 64

typedef float  f32x16 __attribute__((ext_vector_type(16)));
typedef short  bf16x8 __attribute__((ext_vector_type(8)));
typedef short  s16x4  __attribute__((ext_vector_type(4)));
typedef unsigned int u32x4 __attribute__((ext_vector_type(4)));

static __device__ __forceinline__ unsigned short f2bfu(float f) {
    __hip_bfloat16 h = __float2bfloat16(f);
    unsigned short s;
    __builtin_memcpy(&s, &h, 2);
    return s;
}
static __device__ __forceinline__ unsigned packbf(float lo, float hi) {
    return (unsigned)f2bfu(lo) | ((unsigned)f2bfu(hi) << 16);
}
static __device__ __forceinline__ f32x16 fzero16() {
    f32x16 z;
#pragma unroll
    for (int i = 0; i < 16; ++i) z[i] = 0.f;
    return z;
}
static __device__ __forceinline__ bf16x8 bzero8() {
    bf16x8 z;
#pragma unroll
    for (int i = 0; i < 8; ++i) z[i] = 0;
    return z;
}

// P-half processing: __expf -> bf16 pack -> lane^32 partner exchange -> 4 PV
// MFMAs (2 per c-half accumulator).  (R13/R14 verbatim)
static __device__ __forceinline__ void process_phalf(
        const f32x16& s, int hi,
        bf16x8 a0, bf16x8 a1, bf16x8 a2, bf16x8 a3,
        f32x16& accX, f32x16& accY) {
    unsigned g0 = packbf(__expf(s[0]),  __expf(s[1]));
    unsigned g1 = packbf(__expf(s[2]),  __expf(s[3]));
    unsigned g2 = packbf(__expf(s[4]),  __expf(s[5]));
    unsigned g3 = packbf(__expf(s[6]),  __expf(s[7]));
    unsigned g4 = packbf(__expf(s[8]),  __expf(s[9]));
    unsigned g5 = packbf(__expf(s[10]), __expf(s[11]));
    unsigned g6 = packbf(__expf(s[12]), __expf(s[13]));
    unsigned g7 = packbf(__expf(s[14]), __expf(s[15]));
    unsigned r0 = (unsigned)__shfl_xor((int)(hi ? g0 : g2), 32);
    unsigned r1 = (unsigned)__shfl_xor((int)(hi ? g1 : g3), 32);
    unsigned r2 = (unsigned)__shfl_xor((int)(hi ? g4 : g6), 32);
    unsigned r3 = (unsigned)__shfl_xor((int)(hi ? g5 : g7), 32);
    u32x4 b0u, b1u;
    b0u[0] = hi ? r0 : g0;  b0u[1] = hi ? r1 : g1;
    b0u[2] = hi ? g2 : r0;  b0u[3] = hi ? g3 : r1;
    b1u[0] = hi ? r2 : g4;  b1u[1] = hi ? r3 : g5;
    b1u[2] = hi ? g6 : r2;  b1u[3] = hi ? g7 : r3;
    bf16x8 bf0 = __builtin_bit_cast(bf16x8, b0u);
    bf16x8 bf1 = __builtin_bit_cast(bf16x8, b1u);
    accX = __builtin_amdgcn_mfma_f32_32x32x16_bf16(a0, bf0, accX, 0, 0, 0);
    accX = __builtin_amdgcn_mfma_f32_32x32x16_bf16(a1, bf1, accX, 0, 0, 0);
    accY = __builtin_amdgcn_mfma_f32_32x32x16_bf16(a2, bf0, accY, 0, 0, 0);
    accY = __builtin_amdgcn_mfma_f32_32x32x16_bf16(a3, bf1, accY, 0, 0, 0);
}

// ---------------------------------------------------------------------------
// K1: fused projection (q,k,v) via MFMA.
// Records are now 16 shorts: qb[n][16] = {q0..q7, 0,0, 0..0} (slots 8,9
// become lsum hi/lo after stats); kb[n][16] = {k0..k7, -1,-1, 0..0}.
// V written DIRECTLY as bf16 (unscaled): vsT[b*64+c][n].
// proj re-zeroes q aux slots every launch -> graph replays deterministic.
// ---------------------------------------------------------------------------
__global__ __launch_bounds__(256) void proj_all(
        const float* __restrict__ x,
        const float* __restrict__ wq, const float* __restrict__ bq,
        const float* __restrict__ wk, const float* __restrict__ bk,
        const float* __restrict__ wv, const float* __restrict__ bv,
        short* __restrict__ qb, short* __restrict__ kb, short* __restrict__ vsT) {
    int t = threadIdx.x;
    int w = t >> 6, ml = t & 31, hi = (t >> 5) & 1;
    int rt = blockIdx.x >> 7;
    int nt = (blockIdx.x & 127) * 4 + w;
    int ng = nt * 32 + ml;            // b*4096+n
    int b = ng >> 12, nb_ = ng & 4095;
    const float* xc = x + ((size_t)b * CC) * NN + nb_;

    int rg = 32 * rt + ml;            // my A-row (W row)
    const float* wrow =
        rg < 8  ? wq + (size_t)rg * 64 :
        rg < 16 ? wk + (size_t)(rg - 8) * 64 :
        rg < 80 ? wv + (size_t)(rg - 16) * 64 : wq;
    bool wvalid = (rg < 80);

    f32x16 acc = fzero16();
#pragma unroll
    for (int s = 0; s < 4; ++s) {
        int c0 = 16 * s + 8 * hi;
        float xv[8];
#pragma unroll
        for (int j = 0; j < 8; ++j) xv[j] = xc[(size_t)(c0 + j) * NN];
        u32x4 xg;
#pragma unroll
        for (int j = 0; j < 4; ++j) xg[j] = packbf(xv[2 * j], xv[2 * j + 1]);
        bf16x8 xf = __builtin_bit_cast(bf16x8, xg);

        bf16x8 af;
        if (wvalid) {
            float4 f0 = *(const float4*)(wrow + c0);
            float4 f1 = *(const float4*)(wrow + c0 + 4);
            u32x4 ag;
            ag[0] = packbf(f0.x, f0.y); ag[1] = packbf(f0.z, f0.w);
            ag[2] = packbf(f1.x, f1.y); ag[3] = packbf(f1.z, f1.w);
            af = __builtin_bit_cast(bf16x8, ag);
        } else {
            af = bzero8();
        }
        acc = __builtin_amdgcn_mfma_f32_32x32x16_bf16(af, xf, acc, 0, 0, 0);
    }

    if (rt == 0) {
        s16x4 qv, kv;
#pragma unroll
        for (int j = 0; j < 4; ++j) {
            qv[j] = (short)f2bfu(acc[j] + bq[j + 4 * hi]);
            kv[j] = (short)f2bfu(acc[j + 4] + bk[j + 4 * hi]);
        }
        *(s16x4*)(qb + (size_t)ng * 16 + 4 * hi) = qv;
        *(s16x4*)(kb + (size_t)ng * 16 + 4 * hi) = kv;
        // aux slots: q -> zeros (stats fills 8,9); k -> {-1,-1,0,0} in slots 8-11
        s16x4 qaux, kaux;
#pragma unroll
        for (int j = 0; j < 4; ++j) { qaux[j] = 0; kaux[j] = 0; }
        if (!hi) { kaux[0] = (short)f2bfu(-1.0f); kaux[1] = (short)f2bfu(-1.0f); }
        *(s16x4*)(qb + (size_t)ng * 16 + 8 + 4 * hi) = qaux;
        *(s16x4*)(kb + (size_t)ng * 16 + 8 + 4 * hi) = kaux;
#pragma unroll
        for (int r = 8; r < 16; ++r) {            // rows 16-31 -> v c 0-15
            int rowr = (r & 3) + 8 * (r >> 2) + 4 * hi;
            int c = rowr - 16;
            vsT[((size_t)(b * CC + c)) * NN + nb_] = (short)f2bfu(acc[r] + bv[c]);
        }
    } else if (rt == 1) {
#pragma unroll
        for (int r = 0; r < 16; ++r) {            // rows 32-63 -> v c 16-47
            int rowr = (r & 3) + 8 * (r >> 2) + 4 * hi;
            int c = rowr + 16;
            vsT[((size_t)(b * CC + c)) * NN + nb_] = (short)f2bfu(acc[r] + bv[c]);
        }
    } else {
#pragma unroll
        for (int r = 0; r < 8; ++r) {             // rows 64-79 -> v c 48-63
            int rowr = (r & 3) + 8 * (r >> 2) + 4 * hi;
            int c = rowr + 48;
            vsT[((size_t)(b * CC + c)) * NN + nb_] = (short)f2bfu(acc[r] + bv[c]);
        }
    }
}

// ---------------------------------------------------------------------------
// K2: rowsum[n] = sum_m exp(s[n][m]) (R14 main loop, *16 record stride),
// epilogue writes lsum = ln(rowsum) as bf16 hi/lo into qb slots 8,9.
// Lo-half-lane loads only (hi frags zero) -> S is the raw score.
// ---------------------------------------------------------------------------
__global__ __launch_bounds__(512) void stats_mfma(
        const short* __restrict__ qb, const short* __restrict__ kb,
        short* __restrict__ qb_out) {
    int b = blockIdx.x >> 7;
    int nbase = (blockIdx.x & 127) * 32;
    int t = threadIdx.x;
    int w = __builtin_amdgcn_readfirstlane(t >> 6);
    int ml = t & 31, hi = (t >> 5) & 1;

    bf16x8 qf = bzero8();
    if (!hi) qf = *(const bf16x8*)(qb + ((size_t)(b * NN + nbase + ml)) * 16);
    const short* kbb = kb + ((size_t)b * NN) * 16;

    float accl[16];
#pragma unroll
    for (int r = 0; r < 16; ++r) accl[r] = 0.f;

    bf16x8 kf0 = bzero8();
    if (!hi) kf0 = *(const bf16x8*)(kbb + (size_t)(w * 32 + ml) * 16);

    for (int i = 0; i < 16; ++i) {
        int mchn = (i < 15) ? (w + 8 * (i + 1)) : w;
        bf16x8 kf1 = bzero8();
        if (!hi) kf1 = *(const bf16x8*)(kbb + (size_t)(mchn * 32 + ml) * 16);
        f32x16 s = __builtin_amdgcn_mfma_f32_32x32x16_bf16(qf, kf0, fzero16(), 0, 0, 0);
#pragma unroll
        for (int r = 0; r < 16; ++r) accl[r] += __expf(s[r]);
        kf0 = kf1;
    }

#pragma unroll
    for (int r = 0; r < 16; ++r) {
#pragma unroll
        for (int mask = 1; mask <= 16; mask <<= 1)
            accl[r] += __shfl_xor(accl[r], mask);
    }

    __shared__ float rs[32];
    if (t < 32) rs[t] = 0.f;
    __syncthreads();
    if (ml == 0) {
#pragma unroll
        for (int r = 0; r < 16; ++r) {
            int rowr = (r & 3) + 8 * (r >> 2) + 4 * hi;
            atomicAdd(&rs[rowr], accl[r]);
        }
    }
    __syncthreads();

    // epilogue: lsum = ln(rowsum), bf16 hi/lo split into q slots 8,9
    if (t < 32) {
        float ls = logf(rs[t]);
        unsigned short h = f2bfu(ls);
        float lhf = __builtin_bit_cast(float, ((unsigned)h) << 16);
        unsigned short l2 = f2bfu(ls - lhf);
        unsigned pk = (unsigned)h | ((unsigned)l2 << 16);
        *(unsigned*)(qb_out + ((size_t)(b * NN + nbase + t)) * 16 + 8) = pk;
    }
}

// ---------------------------------------------------------------------------
// K3: out[b][c][m] = x + sum_n V[c][n] * exp(s[n][m] - lsum[n]).
// The -lsum comes FREE from the K=16 MFMA (q slots 8,9 x k slots 8,9 = -1).
// Both lane-halves now load real record halves (no if(!hi) zeroing).
// R13/R14 1-chunk software pipeline, all-__expf numerics; V unscaled bf16.
// ---------------------------------------------------------------------------
__global__ __launch_bounds__(512, 2) void attn_pv(
        const short* __restrict__ qb, const short* __restrict__ kb,
        const short* __restrict__ vsT,
        const float* __restrict__ x, float* __restrict__ out) {
    __shared__ float red[4][64][68];

    int b = blockIdx.x >> 6;
    int mbase = (blockIdx.x & 63) << 6;
    int t = threadIdx.x;
    int w = __builtin_amdgcn_readfirstlane(t >> 6);   // 0..7 n-split
    int ml = t & 31, hi = (t >> 5) & 1;

    bf16x8 kf0 = *(const bf16x8*)(kb + ((size_t)(b * NN + mbase + ml)) * 16 + 8 * hi);
    bf16x8 kf1 = *(const bf16x8*)(kb + ((size_t)(b * NN + mbase + 32 + ml)) * 16 + 8 * hi);

    f32x16 accA = fzero16(), accB = fzero16();   // (c0,m0) (c0,m1)
    f32x16 accC = fzero16(), accD = fzero16();   // (c1,m0) (c1,m1)

    const short* qbb = qb + ((size_t)b * NN) * 16;
    const short* v0p = vsT + ((size_t)(b * CC) + ml) * NN;
    const short* v1p = v0p + (size_t)32 * NN;

    // ---- prologue: chunk 0 frags + its S; chunk 1 frags into _c
    int n0 = w * 32;
    bf16x8 qf_c = *(const bf16x8*)(qbb + (size_t)(n0 + ml) * 16 + 8 * hi);
    bf16x8 a00_p = *(const bf16x8*)(v0p + n0 + 8 * hi);
    bf16x8 a01_p = *(const bf16x8*)(v0p + n0 + 16 + 8 * hi);
    bf16x8 a10_p = *(const bf16x8*)(v1p + n0 + 8 * hi);
    bf16x8 a11_p = *(const bf16x8*)(v1p + n0 + 16 + 8 * hi);

    f32x16 s0p = __builtin_amdgcn_mfma_f32_32x32x16_bf16(qf_c, kf0, fzero16(), 0, 0, 0);
    f32x16 s1p = __builtin_amdgcn_mfma_f32_32x32x16_bf16(qf_c, kf1, fzero16(), 0, 0, 0);

    int n1 = (w + 8) * 32;
    qf_c = *(const bf16x8*)(qbb + (size_t)(n1 + ml) * 16 + 8 * hi);
    bf16x8 a00_c = *(const bf16x8*)(v0p + n1 + 8 * hi);
    bf16x8 a01_c = *(const bf16x8*)(v0p + n1 + 16 + 8 * hi);
    bf16x8 a10_c = *(const bf16x8*)(v1p + n1 + 8 * hi);
    bf16x8 a11_c = *(const bf16x8*)(v1p + n1 + 16 + 8 * hi);

    for (int j = 1; j < 16; ++j) {
        // issue loads for chunk j+1 (wrap-reload chunk 0 on last iter, unused)
        int nn = (j < 15) ? (w + 8 * (j + 1)) * 32 : w * 32;
        bf16x8 qf_n = *(const bf16x8*)(qbb + (size_t)(nn + ml) * 16 + 8 * hi);
        bf16x8 a00_n = *(const bf16x8*)(v0p + nn + 8 * hi);
        bf16x8 a01_n = *(const bf16x8*)(v0p + nn + 16 + 8 * hi);
        bf16x8 a10_n = *(const bf16x8*)(v1p + nn + 8 * hi);
        bf16x8 a11_n = *(const bf16x8*)(v1p + nn + 16 + 8 * hi);

        // process chunk j-1 (saved S + its V-frags)
        process_phalf(s0p, hi, a00_p, a01_p, a10_p, a11_p, accA, accC);
        process_phalf(s1p, hi, a00_p, a01_p, a10_p, a11_p, accB, accD);

        // issue chunk j's S-MFMAs (consumed next iter)
        s0p = __builtin_amdgcn_mfma_f32_32x32x16_bf16(qf_c, kf0, fzero16(), 0, 0, 0);
        s1p = __builtin_amdgcn_mfma_f32_32x32x16_bf16(qf_c, kf1, fzero16(), 0, 0, 0);

        a00_p = a00_c; a01_p = a01_c; a10_p = a10_c; a11_p = a11_c;
        a00_c = a00_n; a01_c = a01_n; a10_c = a10_n; a11_c = a11_n;
        qf_c = qf_n;
    }
    // epilogue: chunk 15
    process_phalf(s0p, hi, a00_p, a01_p, a10_p, a11_p, accA, accC);
    process_phalf(s1p, hi, a00_p, a01_p, a10_p, a11_p, accB, accD);

    // two-stage reduce: waves 4-7 dump, waves 0-3 merge, then final sum
    int q4 = w & 3;
    if (w >= 4) {
#pragma unroll
        for (int r = 0; r < 16; ++r) {
            int rowr = (r & 3) + 8 * (r >> 2) + 4 * hi;
            red[q4][rowr][ml]           = accA[r];
            red[q4][rowr][32 + ml]      = accB[r];
            red[q4][rowr + 32][ml]      = accC[r];
            red[q4][rowr + 32][32 + ml] = accD[r];
        }
    }
    __syncthreads();
    if (w < 4) {
#pragma unroll
        for (int r = 0; r < 16; ++r) {
            int rowr = (r & 3) + 8 * (r >> 2) + 4 * hi;
            red[q4][rowr][ml]           += accA[r];
            red[q4][rowr][32 + ml]      += accB[r];
            red[q4][rowr + 32][ml]      += accC[r];
            red[q4][rowr + 32][32 + ml] += accD[r];
        }
    }
    __syncthreads();

    int c = t >> 3;
    int m0 = (t & 7) << 3;
    float4 s0 = *(float4*)&red[0][c][m0];
    float4 s1 = *(float4*)&red[0][c][m0 + 4];
#pragma unroll
    for (int q = 1; q < 4; ++q) {
        float4 a = *(float4*)&red[q][c][m0];
        float4 b4 = *(float4*)&red[q][c][m0 + 4];
        s0.x += a.x; s0.y += a.y; s0.z += a.z; s0.w += a.w;
        s1.x += b4.x; s1.y += b4.y; s1.z += b4.z; s1.w += b4.w;
    }
    size_t idx = ((size_t)(b * CC + c)) * NN + mbase + m0;
    float4 xa = *(const float4*)(x + idx);
    float4 xb = *(const float4*)(x + idx + 4);
    s0.x += xa.x; s0.y += xa.y; s0.z += xa.z; s0.w += xa.w;
    s1.x += xb.x; s1.y += xb.y; s1.z += xb.z; s1.w += xb.w;
    *(float4*)(out + idx) = s0;
    *(float4*)(out + idx + 4) = s1;
}

// ---------------------------------------------------------------------------
extern "C" void kernel_launch(void* const* d_in, const int* in_sizes, int n_in,
                              void* d_out, int out_size, void* d_ws, size_t ws_size,
                              hipStream_t stream) {
    const float* x  = (const float*)d_in[0];
    const float* wq = (const float*)d_in[1];
    const float* bq = (const float*)d_in[2];
    const float* wk = (const float*)d_in[3];
    const float* bk = (const float*)d_in[4];
    const float* wv = (const float*)d_in[5];
    const float* bv = (const float*)d_in[6];
    float* out = (float*)d_out;

    char* ws = (char*)d_ws;
    short* qb  = (short*)(ws);                       // 512 KB (16 shorts/rec)
    short* kb  = (short*)(ws + (512u << 10));        // 512 KB
    short* vsT = (short*)(ws + (1u << 20));          // 2 MB

    proj_all  <<<384, 256, 0, stream>>>(x, wq, bq, wk, bk, wv, bv, qb, kb, vsT);
    stats_mfma<<<512, 512, 0, stream>>>(qb, kb, qb);
    attn_pv   <<<256, 512, 0, stream>>>(qb, kb, vsT, x, out);
}

// Round 16
// 46.150 us; speedup vs baseline: 1.0286x; 1.0286x over previous
//
#include <hip/hip_runtime.h>
#include <hip/hip_bf16.h>
#include <math.h>

#define NN 4096
#define CC 64

typedef float  f32x16 __attribute__((ext_vector_type(16)));
typedef short  bf16x8 __attribute__((ext_vector_type(8)));
typedef short  s16x4  __attribute__((ext_vector_type(4)));
typedef unsigned int u32x4 __attribute__((ext_vector_type(4)));

static __device__ __forceinline__ unsigned short f2bfu(float f) {
    __hip_bfloat16 h = __float2bfloat16(f);
    unsigned short s;
    __builtin_memcpy(&s, &h, 2);
    return s;
}
static __device__ __forceinline__ unsigned packbf(float lo, float hi) {
    return (unsigned)f2bfu(lo) | ((unsigned)f2bfu(hi) << 16);
}
static __device__ __forceinline__ f32x16 fzero16() {
    f32x16 z;
#pragma unroll
    for (int i = 0; i < 16; ++i) z[i] = 0.f;
    return z;
}
static __device__ __forceinline__ bf16x8 bzero8() {
    bf16x8 z;
#pragma unroll
    for (int i = 0; i < 8; ++i) z[i] = 0;
    return z;
}

// P-half processing: __expf -> bf16 pack -> lane^32 partner exchange -> 4 PV
// MFMAs (2 per c-half accumulator).
static __device__ __forceinline__ void process_phalf(
        const f32x16& s, int hi,
        bf16x8 a0, bf16x8 a1, bf16x8 a2, bf16x8 a3,
        f32x16& accX, f32x16& accY) {
    unsigned g0 = packbf(__expf(s[0]),  __expf(s[1]));
    unsigned g1 = packbf(__expf(s[2]),  __expf(s[3]));
    unsigned g2 = packbf(__expf(s[4]),  __expf(s[5]));
    unsigned g3 = packbf(__expf(s[6]),  __expf(s[7]));
    unsigned g4 = packbf(__expf(s[8]),  __expf(s[9]));
    unsigned g5 = packbf(__expf(s[10]), __expf(s[11]));
    unsigned g6 = packbf(__expf(s[12]), __expf(s[13]));
    unsigned g7 = packbf(__expf(s[14]), __expf(s[15]));
    unsigned r0 = (unsigned)__shfl_xor((int)(hi ? g0 : g2), 32);
    unsigned r1 = (unsigned)__shfl_xor((int)(hi ? g1 : g3), 32);
    unsigned r2 = (unsigned)__shfl_xor((int)(hi ? g4 : g6), 32);
    unsigned r3 = (unsigned)__shfl_xor((int)(hi ? g5 : g7), 32);
    u32x4 b0u, b1u;
    b0u[0] = hi ? r0 : g0;  b0u[1] = hi ? r1 : g1;
    b0u[2] = hi ? g2 : r0;  b0u[3] = hi ? g3 : r1;
    b1u[0] = hi ? r2 : g4;  b1u[1] = hi ? r3 : g5;
    b1u[2] = hi ? g6 : r2;  b1u[3] = hi ? g7 : r3;
    bf16x8 bf0 = __builtin_bit_cast(bf16x8, b0u);
    bf16x8 bf1 = __builtin_bit_cast(bf16x8, b1u);
    accX = __builtin_amdgcn_mfma_f32_32x32x16_bf16(a0, bf0, accX, 0, 0, 0);
    accX = __builtin_amdgcn_mfma_f32_32x32x16_bf16(a1, bf1, accX, 0, 0, 0);
    accY = __builtin_amdgcn_mfma_f32_32x32x16_bf16(a2, bf0, accY, 0, 0, 0);
    accY = __builtin_amdgcn_mfma_f32_32x32x16_bf16(a3, bf1, accY, 0, 0, 0);
}

// ---------------------------------------------------------------------------
// K1: fused projection (q,k,v) via MFMA.
// ---------------------------------------------------------------------------
__global__ __launch_bounds__(256) void proj_all(
        const float* __restrict__ x,
        const float* __restrict__ wq, const float* __restrict__ bq,
        const float* __restrict__ wk, const float* __restrict__ bk,
        const float* __restrict__ wv, const float* __restrict__ bv,
        short* __restrict__ qb, short* __restrict__ kb, float* __restrict__ vT) {
    int t = threadIdx.x;
    int w = t >> 6, ml = t & 31, hi = (t >> 5) & 1;
    int rt = blockIdx.x >> 7;
    int nt = (blockIdx.x & 127) * 4 + w;
    int ng = nt * 32 + ml;            // b*4096+n
    int b = ng >> 12, nb_ = ng & 4095;
    const float* xc = x + ((size_t)b * CC) * NN + nb_;

    int rg = 32 * rt + ml;            // my A-row (W row)
    const float* wrow =
        rg < 8  ? wq + (size_t)rg * 64 :
        rg < 16 ? wk + (size_t)(rg - 8) * 64 :
        rg < 80 ? wv + (size_t)(rg - 16) * 64 : wq;
    bool wvalid = (rg < 80);

    f32x16 acc = fzero16();
#pragma unroll
    for (int s = 0; s < 4; ++s) {
        int c0 = 16 * s + 8 * hi;
        float xv[8];
#pragma unroll
        for (int j = 0; j < 8; ++j) xv[j] = xc[(size_t)(c0 + j) * NN];
        u32x4 xg;
#pragma unroll
        for (int j = 0; j < 4; ++j) xg[j] = packbf(xv[2 * j], xv[2 * j + 1]);
        bf16x8 xf = __builtin_bit_cast(bf16x8, xg);

        bf16x8 af;
        if (wvalid) {
            float4 f0 = *(const float4*)(wrow + c0);
            float4 f1 = *(const float4*)(wrow + c0 + 4);
            u32x4 ag;
            ag[0] = packbf(f0.x, f0.y); ag[1] = packbf(f0.z, f0.w);
            ag[2] = packbf(f1.x, f1.y); ag[3] = packbf(f1.z, f1.w);
            af = __builtin_bit_cast(bf16x8, ag);
        } else {
            af = bzero8();
        }
        acc = __builtin_amdgcn_mfma_f32_32x32x16_bf16(af, xf, acc, 0, 0, 0);
    }

    if (rt == 0) {
        s16x4 qv, kv;
#pragma unroll
        for (int j = 0; j < 4; ++j) {
            qv[j] = (short)f2bfu(acc[j] + bq[j + 4 * hi]);
            kv[j] = (short)f2bfu(acc[j + 4] + bk[j + 4 * hi]);
        }
        *(s16x4*)(qb + (size_t)ng * 8 + 4 * hi) = qv;
        *(s16x4*)(kb + (size_t)ng * 8 + 4 * hi) = kv;
#pragma unroll
        for (int r = 8; r < 16; ++r) {            // rows 16-31 -> v c 0-15
            int rowr = (r & 3) + 8 * (r >> 2) + 4 * hi;
            int c = rowr - 16;
            vT[((size_t)(b * CC + c)) * NN + nb_] = acc[r] + bv[c];
        }
    } else if (rt == 1) {
#pragma unroll
        for (int r = 0; r < 16; ++r) {            // rows 32-63 -> v c 16-47
            int rowr = (r & 3) + 8 * (r >> 2) + 4 * hi;
            int c = rowr + 16;
            vT[((size_t)(b * CC + c)) * NN + nb_] = acc[r] + bv[c];
        }
    } else {
#pragma unroll
        for (int r = 0; r < 8; ++r) {             // rows 64-79 -> v c 48-63
            int rowr = (r & 3) + 8 * (r >> 2) + 4 * hi;
            int c = rowr + 48;
            vT[((size_t)(b * CC + c)) * NN + nb_] = acc[r] + bv[c];
        }
    }
}

// ---------------------------------------------------------------------------
// K2: rowsum via MFMA, then FUSED epilogue scales this block's 32-n window
// of V: vsT[c][n] = bf16(vT[c][n] / rowsum[n]).
// Grid 512 = b x 128 n-tiles(32); 8 waves m-split, 16 iters.
// ---------------------------------------------------------------------------
__global__ __launch_bounds__(512) void stats_mfma(
        const short* __restrict__ qb, const short* __restrict__ kb,
        const float* __restrict__ vT, short* __restrict__ vsT) {
    int b = blockIdx.x >> 7;
    int nbase = (blockIdx.x & 127) * 32;
    int t = threadIdx.x;
    int w = __builtin_amdgcn_readfirstlane(t >> 6);
    int ml = t & 31, hi = (t >> 5) & 1;

    bf16x8 qf = bzero8();
    if (!hi) qf = *(const bf16x8*)(qb + ((size_t)(b * NN + nbase + ml)) * 8);
    const short* kbb = kb + ((size_t)b * NN) * 8;

    float accl[16];
#pragma unroll
    for (int r = 0; r < 16; ++r) accl[r] = 0.f;

    bf16x8 kf0 = bzero8();
    if (!hi) kf0 = *(const bf16x8*)(kbb + (size_t)(w * 32 + ml) * 8);

    for (int i = 0; i < 16; ++i) {
        int mchn = (i < 15) ? (w + 8 * (i + 1)) : w;
        bf16x8 kf1 = bzero8();
        if (!hi) kf1 = *(const bf16x8*)(kbb + (size_t)(mchn * 32 + ml) * 8);
        f32x16 s = __builtin_amdgcn_mfma_f32_32x32x16_bf16(qf, kf0, fzero16(), 0, 0, 0);
#pragma unroll
        for (int r = 0; r < 16; ++r) accl[r] += __expf(s[r]);
        kf0 = kf1;
    }

#pragma unroll
    for (int r = 0; r < 16; ++r) {
#pragma unroll
        for (int mask = 1; mask <= 16; mask <<= 1)
            accl[r] += __shfl_xor(accl[r], mask);
    }

    __shared__ float rs[32];
    if (t < 32) rs[t] = 0.f;
    __syncthreads();
    if (ml == 0) {
#pragma unroll
        for (int r = 0; r < 16; ++r) {
            int rowr = (r & 3) + 8 * (r >> 2) + 4 * hi;
            atomicAdd(&rs[rowr], accl[r]);
        }
    }
    __syncthreads();

    // fused epilogue: scale V columns in this 32-n window (single bf16 round)
    float inv = 1.0f / rs[t & 31];
    int nl = nbase + (t & 31);
#pragma unroll
    for (int cl = 0; cl < 4; ++cl) {
        int c = 16 * cl + (t >> 5);
        size_t idx = ((size_t)(b * CC + c)) * NN + nl;
        vsT[idx] = (short)f2bfu(vT[idx] * inv);
    }
}

// ---------------------------------------------------------------------------
// K3: out[b][c][m] = x + sum_n Vs[c][n] * exp(s[n][m]).
// 1-chunk software pipeline, all-__expf numerics.
// Grid 256 = b x 64 m-tiles(64); 8-wave n-split, 16 chunks; no loop barriers.
// ---------------------------------------------------------------------------
__global__ __launch_bounds__(512, 2) void attn_pv(
        const short* __restrict__ qb, const short* __restrict__ kb,
        const short* __restrict__ vsT,
        const float* __restrict__ x, float* __restrict__ out) {
    __shared__ float red[4][64][68];

    int b = blockIdx.x >> 6;
    int mbase = (blockIdx.x & 63) << 6;
    int t = threadIdx.x;
    int w = __builtin_amdgcn_readfirstlane(t >> 6);   // 0..7 n-split
    int ml = t & 31, hi = (t >> 5) & 1;

    bf16x8 kf0 = bzero8(), kf1 = bzero8();
    if (!hi) {
        kf0 = *(const bf16x8*)(kb + ((size_t)(b * NN + mbase + ml)) * 8);
        kf1 = *(const bf16x8*)(kb + ((size_t)(b * NN + mbase + 32 + ml)) * 8);
    }

    f32x16 accA = fzero16(), accB = fzero16();   // (c0,m0) (c0,m1)
    f32x16 accC = fzero16(), accD = fzero16();   // (c1,m0) (c1,m1)

    const short* qbb = qb + ((size_t)b * NN) * 8;
    const short* v0p = vsT + ((size_t)(b * CC) + ml) * NN;
    const short* v1p = v0p + (size_t)32 * NN;

    // ---- prologue: chunk 0 frags + its S; chunk 1 frags into _c
    int n0 = w * 32;
    bf16x8 qf_c = bzero8();
    if (!hi) qf_c = *(const bf16x8*)(qbb + (size_t)(n0 + ml) * 8);
    bf16x8 a00_p = *(const bf16x8*)(v0p + n0 + 8 * hi);
    bf16x8 a01_p = *(const bf16x8*)(v0p + n0 + 16 + 8 * hi);
    bf16x8 a10_p = *(const bf16x8*)(v1p + n0 + 8 * hi);
    bf16x8 a11_p = *(const bf16x8*)(v1p + n0 + 16 + 8 * hi);

    f32x16 s0p = __builtin_amdgcn_mfma_f32_32x32x16_bf16(qf_c, kf0, fzero16(), 0, 0, 0);
    f32x16 s1p = __builtin_amdgcn_mfma_f32_32x32x16_bf16(qf_c, kf1, fzero16(), 0, 0, 0);

    int n1 = (w + 8) * 32;
    if (!hi) qf_c = *(const bf16x8*)(qbb + (size_t)(n1 + ml) * 8);
    else     qf_c = bzero8();
    bf16x8 a00_c = *(const bf16x8*)(v0p + n1 + 8 * hi);
    bf16x8 a01_c = *(const bf16x8*)(v0p + n1 + 16 + 8 * hi);
    bf16x8 a10_c = *(const bf16x8*)(v1p + n1 + 8 * hi);
    bf16x8 a11_c = *(const bf16x8*)(v1p + n1 + 16 + 8 * hi);

    for (int j = 1; j < 16; ++j) {
        // issue loads for chunk j+1 (wrap-reload chunk 0 on last iter, unused)
        int nn = (j < 15) ? (w + 8 * (j + 1)) * 32 : w * 32;
        bf16x8 qf_n = bzero8();
        if (!hi) qf_n = *(const bf16x8*)(qbb + (size_t)(nn + ml) * 8);
        bf16x8 a00_n = *(const bf16x8*)(v0p + nn + 8 * hi);
        bf16x8 a01_n = *(const bf16x8*)(v0p + nn + 16 + 8 * hi);
        bf16x8 a10_n = *(const bf16x8*)(v1p + nn + 8 * hi);
        bf16x8 a11_n = *(const bf16x8*)(v1p + nn + 16 + 8 * hi);

        // process chunk j-1 (saved S + its V-frags)
        process_phalf(s0p, hi, a00_p, a01_p, a10_p, a11_p, accA, accC);
        process_phalf(s1p, hi, a00_p, a01_p, a10_p, a11_p, accB, accD);

        // issue chunk j's S-MFMAs (consumed next iter)
        s0p = __builtin_amdgcn_mfma_f32_32x32x16_bf16(qf_c, kf0, fzero16(), 0, 0, 0);
        s1p = __builtin_amdgcn_mfma_f32_32x32x16_bf16(qf_c, kf1, fzero16(), 0, 0, 0);

        a00_p = a00_c; a01_p = a01_c; a10_p = a10_c; a11_p = a11_c;
        a00_c = a00_n; a01_c = a01_n; a10_c = a10_n; a11_c = a11_n;
        qf_c = qf_n;
    }
    // epilogue: chunk 15
    process_phalf(s0p, hi, a00_p, a01_p, a10_p, a11_p, accA, accC);
    process_phalf(s1p, hi, a00_p, a01_p, a10_p, a11_p, accB, accD);

    // two-stage reduce: waves 4-7 dump, waves 0-3 merge, then final sum
    int q4 = w & 3;
    if (w >= 4) {
#pragma unroll
        for (int r = 0; r < 16; ++r) {
            int rowr = (r & 3) + 8 * (r >> 2) + 4 * hi;
            red[q4][rowr][ml]           = accA[r];
            red[q4][rowr][32 + ml]      = accB[r];
            red[q4][rowr + 32][ml]      = accC[r];
            red[q4][rowr + 32][32 + ml] = accD[r];
        }
    }
    __syncthreads();
    if (w < 4) {
#pragma unroll
        for (int r = 0; r < 16; ++r) {
            int rowr = (r & 3) + 8 * (r >> 2) + 4 * hi;
            red[q4][rowr][ml]           += accA[r];
            red[q4][rowr][32 + ml]      += accB[r];
            red[q4][rowr + 32][ml]      += accC[r];
            red[q4][rowr + 32][32 + ml] += accD[r];
        }
    }
    __syncthreads();

    int c = t >> 3;
    int m0 = (t & 7) << 3;
    float4 s0 = *(float4*)&red[0][c][m0];
    float4 s1 = *(float4*)&red[0][c][m0 + 4];
#pragma unroll
    for (int q = 1; q < 4; ++q) {
        float4 a = *(float4*)&red[q][c][m0];
        float4 b4 = *(float4*)&red[q][c][m0 + 4];
        s0.x += a.x; s0.y += a.y; s0.z += a.z; s0.w += a.w;
        s1.x += b4.x; s1.y += b4.y; s1.z += b4.z; s1.w += b4.w;
    }
    size_t idx = ((size_t)(b * CC + c)) * NN + mbase + m0;
    float4 xa = *(const float4*)(x + idx);
    float4 xb = *(const float4*)(x + idx + 4);
    s0.x += xa.x; s0.y += xa.y; s0.z += xa.z; s0.w += xa.w;
    s1.x += xb.x; s1.y += xb.y; s1.z += xb.z; s1.w += xb.w;
    *(float4*)(out + idx) = s0;
    *(float4*)(out + idx + 4) = s1;
}

// ---------------------------------------------------------------------------
extern "C" void kernel_launch(void* const* d_in, const int* in_sizes, int n_in,
                              void* d_out, int out_size, void* d_ws, size_t ws_size,
                              hipStream_t stream) {
    const float* x  = (const float*)d_in[0];
    const float* wq = (const float*)d_in[1];
    const float* bq = (const float*)d_in[2];
    const float* wk = (const float*)d_in[3];
    const float* bk = (const float*)d_in[4];
    const float* wv = (const float*)d_in[5];
    const float* bv = (const float*)d_in[6];
    float* out = (float*)d_out;

    char* ws = (char*)d_ws;
    short* qb  = (short*)(ws);                              // 256 KB
    short* kb  = (short*)(ws + (256u << 10));               // 256 KB
    float* vT  = (float*)(ws + (512u << 10));               // 4 MB
    short* vsT = (short*)(ws + (512u << 10) + (4u << 20));  // 2 MB

    proj_all  <<<384, 256, 0, stream>>>(x, wq, bq, wk, bk, wv, bv, qb, kb, vT);
    stats_mfma<<<512, 512, 0, stream>>>(qb, kb, vT, vsT);
    attn_pv   <<<256, 512, 0, stream>>>(qb, kb, vsT, x, out);
}